// Round 2
// baseline (656.892 us; speedup 1.0000x reference)
//
#include <hip/hip_runtime.h>
#include <hip/hip_bf16.h>

// Sorted segment-sum, ownership inverted: each wave owns SEGS_PER_WAVE
// contiguous segment ids, binary-searches the sorted idx array for its exact
// fragment span, accumulates runs in registers, and writes each output
// segment exactly once (zero for empty segments). No memset, no atomics.
// lane = embedding dim (D=64 == wavefront size -> 256B coalesced accesses).

#define SEGS_PER_WAVE 64
#define D_EMBED 64

__device__ inline int lower_bound(const int* __restrict__ idx, int n, int v) {
    int lo = 0, hi = n;
    while (lo < hi) {
        int mid = (lo + hi) >> 1;      // uniform across wave
        if (idx[mid] < v) lo = mid + 1; else hi = mid;
    }
    return lo;
}

__global__ void seg_sum_kernel(const float* __restrict__ emb,
                               const int* __restrict__ idx,
                               float* __restrict__ out,
                               int n_frag, int n_seg) {
    const int gtid = blockIdx.x * blockDim.x + threadIdx.x;
    const int wave = gtid >> 6;
    const int lane = threadIdx.x & 63;

    const int s0 = wave * SEGS_PER_WAVE;
    if (s0 >= n_seg) return;
    const int s1 = min(s0 + SEGS_PER_WAVE, n_seg);

    // Exact fragment span for this wave's segment range (idx is sorted).
    int       f  = lower_bound(idx, n_frag, s0);
    const int f1 = lower_bound(idx, n_frag, s1);

    for (int s = s0; s < s1; ++s) {
        float acc = 0.0f;
        while (f < f1 && idx[f] == s) {        // wave-uniform condition
            acc += emb[(long)f * D_EMBED + lane];  // 256B coalesced
            ++f;
        }
        out[(long)s * D_EMBED + lane] = acc;   // single coalesced store
    }
}

extern "C" void kernel_launch(void* const* d_in, const int* in_sizes, int n_in,
                              void* d_out, int out_size, void* d_ws, size_t ws_size,
                              hipStream_t stream) {
    const float* emb = (const float*)d_in[0];
    const int*   idx = (const int*)d_in[1];
    float*       out = (float*)d_out;

    const int n_frag = in_sizes[0] / D_EMBED;      // 4,000,000
    const int n_seg  = out_size / D_EMBED;         // cell_n * gene_n = 1,000,000

    const int n_waves  = (n_seg + SEGS_PER_WAVE - 1) / SEGS_PER_WAVE;
    const int block    = 256;                      // 4 waves / block
    const int waves_pb = block / 64;
    const int grid     = (n_waves + waves_pb - 1) / waves_pb;

    seg_sum_kernel<<<grid, block, 0, stream>>>(emb, idx, out, n_frag, n_seg);
}

// Round 3
// 294.374 us; speedup vs baseline: 2.2315x; 2.2315x over previous
//
#include <hip/hip_runtime.h>
#include <hip/hip_bf16.h>

// Sorted segment-sum, segment-ownership (no atomics, no memset):
// each wave owns SEGS_PER_WAVE contiguous segments, binary-searches its exact
// fragment span, then streams fragments in batches of 16:
//   - 1 coalesced idx load (lanes 0..15) per batch; readlane -> SALU branches
//   - 16 embedding loads preloaded into registers (immediate-offset cluster)
//   - boundary walk stores each owned segment exactly once (zeros if empty)
// lane = embedding dim (D=64 == wavefront -> 256B coalesced per fragment).

#define SEGS_PER_WAVE 64
#define D_EMBED 64
#define BATCH 16

__device__ inline int lower_bound(const int* __restrict__ idx, int n, int v) {
    int lo = 0, hi = n;
    while (lo < hi) {
        int mid = (lo + hi) >> 1;
        if (idx[mid] < v) lo = mid + 1; else hi = mid;
    }
    return lo;
}

__global__ __launch_bounds__(256) void seg_sum_kernel(
        const float* __restrict__ emb,
        const int*   __restrict__ idx,
        float*       __restrict__ out,
        int n_frag, int n_seg) {
    const int gtid = blockIdx.x * blockDim.x + threadIdx.x;
    const int wave = gtid >> 6;
    const int lane = threadIdx.x & 63;

    const int s0 = wave * SEGS_PER_WAVE;
    if (s0 >= n_seg) return;
    const int s1 = min(s0 + SEGS_PER_WAVE, n_seg);

    int       f  = lower_bound(idx, n_frag, s0);
    const int f1 = lower_bound(idx, n_frag, s1);

    int   cur = -1;    // segment currently accumulating (-1 = none yet)
    int   nxt = s0;    // next segment id still needing its output written
    float acc = 0.0f;

    while (f < f1) {
        const int take = min(BATCH, f1 - f);
        // one 64B line: lanes 0..15 fetch the next 16 segment ids
        int my_seg = idx[f + (lane & (BATCH - 1))];

        if (take == BATCH) {
            // ---- preload 16 fragments into registers (load cluster) ----
            float v[BATCH];
            const float* base = emb + (long)f * D_EMBED + lane;
#pragma unroll
            for (int j = 0; j < BATCH; ++j)
                v[j] = base[j * D_EMBED];          // imm offset j*256B

            // ---- boundary walk: branches resolve from registers ----
#pragma unroll
            for (int j = 0; j < BATCH; ++j) {
                int s = __builtin_amdgcn_readlane(my_seg, j);
                if (s != cur) {                    // wave-uniform, rare
                    if (cur >= 0) { out[(long)cur * D_EMBED + lane] = acc; nxt = cur + 1; }
                    for (int z = nxt; z < s; ++z)  // empty segments -> zeros
                        out[(long)z * D_EMBED + lane] = 0.0f;
                    cur = s; nxt = s; acc = 0.0f;
                }
                acc += v[j];
            }
        } else {
            // tail (< 16 fragments)
            for (int j = 0; j < take; ++j) {
                float v = emb[(long)(f + j) * D_EMBED + lane];
                int s = __builtin_amdgcn_readlane(my_seg, j);
                if (s != cur) {
                    if (cur >= 0) { out[(long)cur * D_EMBED + lane] = acc; nxt = cur + 1; }
                    for (int z = nxt; z < s; ++z)
                        out[(long)z * D_EMBED + lane] = 0.0f;
                    cur = s; nxt = s; acc = 0.0f;
                }
                acc += v;
            }
        }
        f += take;
    }

    // final flush + trailing empty segments
    if (cur >= 0) { out[(long)cur * D_EMBED + lane] = acc; nxt = cur + 1; }
    for (int z = nxt; z < s1; ++z)
        out[(long)z * D_EMBED + lane] = 0.0f;
}

extern "C" void kernel_launch(void* const* d_in, const int* in_sizes, int n_in,
                              void* d_out, int out_size, void* d_ws, size_t ws_size,
                              hipStream_t stream) {
    const float* emb = (const float*)d_in[0];
    const int*   idx = (const int*)d_in[1];
    float*       out = (float*)d_out;

    const int n_frag = in_sizes[0] / D_EMBED;   // 4,000,000
    const int n_seg  = out_size / D_EMBED;      // 1,000,000

    const int n_waves  = (n_seg + SEGS_PER_WAVE - 1) / SEGS_PER_WAVE;
    const int block    = 256;                   // 4 waves / block
    const int waves_pb = block / 64;
    const int grid     = (n_waves + waves_pb - 1) / waves_pb;

    seg_sum_kernel<<<grid, block, 0, stream>>>(emb, idx, out, n_frag, n_seg);
}

// Round 4
// 287.538 us; speedup vs baseline: 2.2845x; 1.0238x over previous
//
#include <hip/hip_runtime.h>
#include <hip/hip_bf16.h>

// Sorted segment-sum, segment-ownership (no atomics, no memset), 2-deep
// software pipeline: prefetch batch k+1 (1 idx line + 16 embedding rows)
// before walking batch k, so ~32 emb loads stay in flight per wave.
// Named A/B buffers (no runtime-indexed arrays -> stays in VGPRs).
// lane = embedding dim (D=64 == wavefront -> 256B coalesced per fragment).

#define SEGS_PER_WAVE 64
#define D_EMBED 64
#define BATCH 16

__device__ inline int lower_bound(const int* __restrict__ idx, int n, int v) {
    int lo = 0, hi = n;
    while (lo < hi) {
        int mid = (lo + hi) >> 1;
        if (idx[mid] < v) lo = mid + 1; else hi = mid;
    }
    return lo;
}

__global__ __launch_bounds__(256) void seg_sum_kernel(
        const float* __restrict__ emb,
        const int*   __restrict__ idx,
        float*       __restrict__ out,
        int n_frag, int n_seg) {
    const int gtid = blockIdx.x * blockDim.x + threadIdx.x;
    const int wave = gtid >> 6;
    const int lane = threadIdx.x & 63;

    const int s0 = wave * SEGS_PER_WAVE;
    if (s0 >= n_seg) return;
    const int s1 = min(s0 + SEGS_PER_WAVE, n_seg);

    int       f  = lower_bound(idx, n_frag, s0);
    const int f1 = lower_bound(idx, n_frag, s1);

    int   cur = -1;    // segment currently accumulating (-1 = none yet)
    int   nxt = s0;    // next segment id still needing its output written
    float acc = 0.0f;

    float vA[BATCH], vB[BATCH];
    int   mA = 0, mB = 0;

    auto LOAD_A = [&](long fb) {
        mA = idx[fb + (lane & (BATCH - 1))];        // one 64B line, broadcast
        const float* base = emb + fb * D_EMBED + lane;
#pragma unroll
        for (int j = 0; j < BATCH; ++j) vA[j] = base[j * D_EMBED];
    };
    auto LOAD_B = [&](long fb) {
        mB = idx[fb + (lane & (BATCH - 1))];
        const float* base = emb + fb * D_EMBED + lane;
#pragma unroll
        for (int j = 0; j < BATCH; ++j) vB[j] = base[j * D_EMBED];
    };
    auto WALK = [&](const float* v, int mseg) {
#pragma unroll
        for (int j = 0; j < BATCH; ++j) {
            int s = __builtin_amdgcn_readlane(mseg, j);
            if (s != cur) {                          // wave-uniform, ~1-in-4
                if (cur >= 0) { out[(long)cur * D_EMBED + lane] = acc; nxt = cur + 1; }
                for (int z = nxt; z < s; ++z)        // empty segments -> zeros
                    out[(long)z * D_EMBED + lane] = 0.0f;
                cur = s; nxt = s; acc = 0.0f;
            }
            acc += v[j];
        }
    };

    const int nfull = (f1 - f) >> 4;                 // full 16-frag batches
    long fcur = f;
    int  b = 0;
    if (nfull > 0) LOAD_A(fcur);
    while (b < nfull) {
        if (b + 1 < nfull) LOAD_B(fcur + BATCH);     // prefetch before walk
        WALK(vA, mA);
        fcur += BATCH; ++b;
        if (b >= nfull) break;
        if (b + 1 < nfull) LOAD_A(fcur + BATCH);
        WALK(vB, mB);
        fcur += BATCH; ++b;
    }

    // tail: < 16 fragments
    for (long ff = (long)f + (long)nfull * BATCH; ff < f1; ++ff) {
        int   s = idx[ff];                           // uniform
        float v = emb[ff * D_EMBED + lane];
        if (s != cur) {
            if (cur >= 0) { out[(long)cur * D_EMBED + lane] = acc; nxt = cur + 1; }
            for (int z = nxt; z < s; ++z)
                out[(long)z * D_EMBED + lane] = 0.0f;
            cur = s; nxt = s; acc = 0.0f;
        }
        acc += v;
    }

    // final flush + trailing empty segments
    if (cur >= 0) { out[(long)cur * D_EMBED + lane] = acc; nxt = cur + 1; }
    for (int z = nxt; z < s1; ++z)
        out[(long)z * D_EMBED + lane] = 0.0f;
}

extern "C" void kernel_launch(void* const* d_in, const int* in_sizes, int n_in,
                              void* d_out, int out_size, void* d_ws, size_t ws_size,
                              hipStream_t stream) {
    const float* emb = (const float*)d_in[0];
    const int*   idx = (const int*)d_in[1];
    float*       out = (float*)d_out;

    const int n_frag = in_sizes[0] / D_EMBED;   // 4,000,000
    const int n_seg  = out_size / D_EMBED;      // 1,000,000

    const int n_waves  = (n_seg + SEGS_PER_WAVE - 1) / SEGS_PER_WAVE;
    const int block    = 256;                   // 4 waves / block
    const int waves_pb = block / 64;
    const int grid     = (n_waves + waves_pb - 1) / waves_pb;

    seg_sum_kernel<<<grid, block, 0, stream>>>(emb, idx, out, n_frag, n_seg);
}

// Round 5
// 253.590 us; speedup vs baseline: 2.5904x; 1.1339x over previous
//
#include <hip/hip_runtime.h>
#include <hip/hip_bf16.h>

// Sorted segment-sum, segment-ownership (no atomics, no memset), 2-deep
// software pipeline + NONTEMPORAL cache policy on the zero-reuse streams:
//   - embedding reads (1 GB, touched once)  -> nontemporal load (no L2 alloc)
//   - output stores   (256 MB, write once)  -> nontemporal store
//   - idx loads stay cached (reused by binary search; 16 MB fits L3)
// lane = embedding dim (D=64 == wavefront -> 256B coalesced per fragment).

#define SEGS_PER_WAVE 64
#define D_EMBED 64
#define BATCH 16

__device__ inline int lower_bound(const int* __restrict__ idx, int n, int v) {
    int lo = 0, hi = n;
    while (lo < hi) {
        int mid = (lo + hi) >> 1;
        if (idx[mid] < v) lo = mid + 1; else hi = mid;
    }
    return lo;
}

__global__ __launch_bounds__(256) void seg_sum_kernel(
        const float* __restrict__ emb,
        const int*   __restrict__ idx,
        float*       __restrict__ out,
        int n_frag, int n_seg) {
    const int gtid = blockIdx.x * blockDim.x + threadIdx.x;
    const int wave = gtid >> 6;
    const int lane = threadIdx.x & 63;

    const int s0 = wave * SEGS_PER_WAVE;
    if (s0 >= n_seg) return;
    const int s1 = min(s0 + SEGS_PER_WAVE, n_seg);

    int       f  = lower_bound(idx, n_frag, s0);
    const int f1 = lower_bound(idx, n_frag, s1);

    int   cur = -1;    // segment currently accumulating (-1 = none yet)
    int   nxt = s0;    // next segment id still needing its output written
    float acc = 0.0f;

    float vA[BATCH], vB[BATCH];
    int   mA = 0, mB = 0;

    auto LOAD_A = [&](long fb) {
        mA = idx[fb + (lane & (BATCH - 1))];        // one 64B line, broadcast
        const float* base = emb + fb * D_EMBED + lane;
#pragma unroll
        for (int j = 0; j < BATCH; ++j)
            vA[j] = __builtin_nontemporal_load(base + j * D_EMBED);
    };
    auto LOAD_B = [&](long fb) {
        mB = idx[fb + (lane & (BATCH - 1))];
        const float* base = emb + fb * D_EMBED + lane;
#pragma unroll
        for (int j = 0; j < BATCH; ++j)
            vB[j] = __builtin_nontemporal_load(base + j * D_EMBED);
    };
    auto WALK = [&](const float* v, int mseg) {
#pragma unroll
        for (int j = 0; j < BATCH; ++j) {
            int s = __builtin_amdgcn_readlane(mseg, j);
            if (s != cur) {                          // wave-uniform, ~1-in-4
                if (cur >= 0) {
                    __builtin_nontemporal_store(acc, &out[(long)cur * D_EMBED + lane]);
                    nxt = cur + 1;
                }
                for (int z = nxt; z < s; ++z)        // empty segments -> zeros
                    __builtin_nontemporal_store(0.0f, &out[(long)z * D_EMBED + lane]);
                cur = s; nxt = s; acc = 0.0f;
            }
            acc += v[j];
        }
    };

    const int nfull = (f1 - f) >> 4;                 // full 16-frag batches
    long fcur = f;
    int  b = 0;
    if (nfull > 0) LOAD_A(fcur);
    while (b < nfull) {
        if (b + 1 < nfull) LOAD_B(fcur + BATCH);     // prefetch before walk
        WALK(vA, mA);
        fcur += BATCH; ++b;
        if (b >= nfull) break;
        if (b + 1 < nfull) LOAD_A(fcur + BATCH);
        WALK(vB, mB);
        fcur += BATCH; ++b;
    }

    // tail: < 16 fragments
    for (long ff = (long)f + (long)nfull * BATCH; ff < f1; ++ff) {
        int   s = idx[ff];                           // uniform
        float v = emb[ff * D_EMBED + lane];
        if (s != cur) {
            if (cur >= 0) {
                __builtin_nontemporal_store(acc, &out[(long)cur * D_EMBED + lane]);
                nxt = cur + 1;
            }
            for (int z = nxt; z < s; ++z)
                __builtin_nontemporal_store(0.0f, &out[(long)z * D_EMBED + lane]);
            cur = s; nxt = s; acc = 0.0f;
        }
        acc += v;
    }

    // final flush + trailing empty segments
    if (cur >= 0) {
        __builtin_nontemporal_store(acc, &out[(long)cur * D_EMBED + lane]);
        nxt = cur + 1;
    }
    for (int z = nxt; z < s1; ++z)
        __builtin_nontemporal_store(0.0f, &out[(long)z * D_EMBED + lane]);
}

extern "C" void kernel_launch(void* const* d_in, const int* in_sizes, int n_in,
                              void* d_out, int out_size, void* d_ws, size_t ws_size,
                              hipStream_t stream) {
    const float* emb = (const float*)d_in[0];
    const int*   idx = (const int*)d_in[1];
    float*       out = (float*)d_out;

    const int n_frag = in_sizes[0] / D_EMBED;   // 4,000,000
    const int n_seg  = out_size / D_EMBED;      // 1,000,000

    const int n_waves  = (n_seg + SEGS_PER_WAVE - 1) / SEGS_PER_WAVE;
    const int block    = 256;                   // 4 waves / block
    const int waves_pb = block / 64;
    const int grid     = (n_waves + waves_pb - 1) / waves_pb;

    seg_sum_kernel<<<grid, block, 0, stream>>>(emb, idx, out, n_frag, n_seg);
}